// Round 1
// baseline (90.073 us; speedup 1.0000x reference)
//
#include <hip/hip_runtime.h>

#define WAVE 64

// Kernel 1: find segment boundaries of the sorted ray_id array.
__global__ __launch_bounds__(256) void seg_bounds_kernel(
    const int* __restrict__ ray_id, int n,
    int* __restrict__ seg_start, int* __restrict__ seg_end)
{
    int i = blockIdx.x * blockDim.x + threadIdx.x;
    if (i >= n) return;
    int rid = ray_id[i];
    if (i == 0 || ray_id[i - 1] != rid) seg_start[rid] = i;
    if (i == n - 1 || ray_id[i + 1] != rid) seg_end[rid] = i + 1;
}

// Kernel 2: one wave (64 lanes) per ray. Computes:
//  - transmittance[i] = exp(exclusive cumsum of log(clip(1-alpha)) within ray)
//  - bg_transmittance[r] = exp(total log-sum)
//  - integrated_3d / integrated_1d = segment sums of value*weight
//  - sum_per_ray = segment sum of sample_values, broadcast back to sum_per_sample
__global__ __launch_bounds__(256) void ray_kernel(
    const float* __restrict__ alpha,
    const float* __restrict__ values3d,
    const float* __restrict__ values1d,
    const float* __restrict__ weights,
    const float* __restrict__ sample_values,
    const int*   __restrict__ seg_start,
    const int*   __restrict__ seg_end,
    float* __restrict__ out_T,    // [N]
    float* __restrict__ out_bg,   // [R]
    float* __restrict__ out_i3,   // [R,3]
    float* __restrict__ out_i1,   // [R]
    float* __restrict__ out_spr,  // [R,3]
    float* __restrict__ out_sps,  // [N,3]
    int R)
{
    int lane = threadIdx.x & (WAVE - 1);
    int wave = threadIdx.x >> 6;
    int r = blockIdx.x * (blockDim.x >> 6) + wave;
    if (r >= R) return;

    int s0 = seg_start[r];
    int s1 = seg_end[r];

    float c = 0.0f;  // running log-sum carry across 64-wide chunks
    float i3x = 0.f, i3y = 0.f, i3z = 0.f, i1 = 0.f;
    float sx = 0.f, sy = 0.f, sz = 0.f;

    for (int base = s0; base < s1; base += WAVE) {
        int i = base + lane;
        bool act = i < s1;
        float logv = 0.0f;
        if (act) {
            float om = 1.0f - alpha[i];
            om = fminf(fmaxf(om, 1e-7f), 1.0f);
            logv = logf(om);
        }
        // 64-lane inclusive scan of logv
        float incl = logv;
        #pragma unroll
        for (int d = 1; d < WAVE; d <<= 1) {
            float o = __shfl_up(incl, d, WAVE);
            if (lane >= d) incl += o;
        }
        float excl = incl - logv;
        if (act) {
            out_T[i] = expf(c + excl);
            float w = weights[i];
            i3x += values3d[3 * i + 0] * w;
            i3y += values3d[3 * i + 1] * w;
            i3z += values3d[3 * i + 2] * w;
            i1  += values1d[i] * w;
            sx  += sample_values[3 * i + 0];
            sy  += sample_values[3 * i + 1];
            sz  += sample_values[3 * i + 2];
        }
        c += __shfl(incl, WAVE - 1, WAVE);  // inactive lanes contributed 0
    }

    // wave all-reduce (every lane ends with the total)
    #pragma unroll
    for (int d = 1; d < WAVE; d <<= 1) {
        i3x += __shfl_xor(i3x, d, WAVE);
        i3y += __shfl_xor(i3y, d, WAVE);
        i3z += __shfl_xor(i3z, d, WAVE);
        i1  += __shfl_xor(i1,  d, WAVE);
        sx  += __shfl_xor(sx,  d, WAVE);
        sy  += __shfl_xor(sy,  d, WAVE);
        sz  += __shfl_xor(sz,  d, WAVE);
    }

    if (lane == 0) {
        out_bg[r] = expf(c);
        out_i3[3 * r + 0] = i3x;
        out_i3[3 * r + 1] = i3y;
        out_i3[3 * r + 2] = i3z;
        out_i1[r] = i1;
        out_spr[3 * r + 0] = sx;
        out_spr[3 * r + 1] = sy;
        out_spr[3 * r + 2] = sz;
    }

    // broadcast sum_per_ray back over the segment (fused sum_per_sample)
    for (int base = s0; base < s1; base += WAVE) {
        int i = base + lane;
        if (i < s1) {
            out_sps[3 * i + 0] = sx;
            out_sps[3 * i + 1] = sy;
            out_sps[3 * i + 2] = sz;
        }
    }
}

extern "C" void kernel_launch(void* const* d_in, const int* in_sizes, int n_in,
                              void* d_out, int out_size, void* d_ws, size_t ws_size,
                              hipStream_t stream) {
    const float* alpha = (const float*)d_in[0];
    const float* v3    = (const float*)d_in[1];
    const float* v1    = (const float*)d_in[2];
    const float* w     = (const float*)d_in[3];
    const float* sv    = (const float*)d_in[4];
    const int*   rid   = (const int*)d_in[5];

    int N = in_sizes[0];
    int R = (out_size - 4 * N) / 8;  // out = N + R + 3R + R + 3R + 3N

    int* seg_start = (int*)d_ws;
    int* seg_end   = seg_start + R;
    hipMemsetAsync(d_ws, 0, (size_t)2 * R * sizeof(int), stream);

    float* out     = (float*)d_out;
    float* out_T   = out;
    float* out_bg  = out + N;
    float* out_i3  = out_bg + R;
    float* out_i1  = out_i3 + 3 * (size_t)R;
    float* out_spr = out_i1 + R;
    float* out_sps = out_spr + 3 * (size_t)R;

    seg_bounds_kernel<<<(N + 255) / 256, 256, 0, stream>>>(rid, N, seg_start, seg_end);

    int wavesPerBlock = 4;  // 256 threads
    int blocks = (R + wavesPerBlock - 1) / wavesPerBlock;
    ray_kernel<<<blocks, 256, 0, stream>>>(alpha, v3, v1, w, sv, seg_start, seg_end,
                                           out_T, out_bg, out_i3, out_i1, out_spr,
                                           out_sps, R);
}